// Round 2
// baseline (52.106 us; speedup 1.0000x reference)
//
#include <hip/hip_runtime.h>
#include <math.h>

#define OBS 512
#define ATT 128
#define RPB 4   // (b,e) rows per block

// Kernel 0: ws <- Wphi^T  (WphiT[k][dd] = Wphi[dd][k]), 128x512 fp32 = 256KB
__global__ void transpose_wphi_k(const float* __restrict__ wphi,
                                 float* __restrict__ wphiT) {
  int idx = blockIdx.x * 256 + threadIdx.x;   // 0..65535
  int k  = idx >> 9;
  int dd = idx & 511;
  wphiT[idx] = wphi[dd * ATT + k];
}

__device__ __forceinline__ void fma4(float4& a, float s, float4 w) {
  a.x = fmaf(s, w.x, a.x);
  a.y = fmaf(s, w.y, a.y);
  a.z = fmaf(s, w.z, a.z);
  a.w = fmaf(s, w.w, a.w);
}

// 4 blocks/CU x 4 waves = 16 waves/CU target occupancy
__launch_bounds__(256, 4)
__global__ void entity_attn_k(const float* __restrict__ A,     // (4096,512)
                              const float* __restrict__ V,     // (4096,16,512)
                              const float* __restrict__ Wpsi,  // (512,128)
                              const float* __restrict__ WphiT, // (128,512) ws
                              float* __restrict__ Out)         // (4096,16)
{
  // S layout (floats), 26KB total:
  //  [0,2048):    At[d][4]    (stage -> B)   THEN uS[4][512] (C -> D)
  //  [2048,6144): qpart[ds8][r4][k128]  (B -> reduce)
  //  [6144,6656): qt[k][4]    (reduce -> C)
  __shared__ __align__(16) float S[6656];

  const int tid  = threadIdx.x;
  const int lane = tid & 63;
  const int wave = tid >> 6;          // 0..3
  const int g0   = blockIdx.x * RPB;

  // ---- stage A transposed: At[d][r] = A[g0+r][d] ----
  {
    const int r = tid & 3;
    const int c = tid >> 2;           // 0..63
    const float4* a4 = (const float4*)(A + (size_t)(g0 + r) * OBS) + c * 2;
    float4 v0 = a4[0], v1 = a4[1];
    const int d0 = c * 8;
    S[(d0+0)*4+r] = v0.x; S[(d0+1)*4+r] = v0.y;
    S[(d0+2)*4+r] = v0.z; S[(d0+3)*4+r] = v0.w;
    S[(d0+4)*4+r] = v1.x; S[(d0+5)*4+r] = v1.y;
    S[(d0+6)*4+r] = v1.z; S[(d0+7)*4+r] = v1.w;
  }
  __syncthreads();

  // ---- phase B: q partials. thread = (k-quad kg, d-split ds) ----
  // Wpsi read exactly once per block (coalesced float4), At via LDS broadcast.
  {
    const int kg = tid & 31;          // k0 = kg*4
    const int ds = tid >> 5;          // 0..7, d-range ds*64..+64
    float4 acc0 = make_float4(0.f,0.f,0.f,0.f);
    float4 acc1 = acc0, acc2 = acc0, acc3 = acc0;
    const float4* wp4 = (const float4*)Wpsi;
    const float4* at4 = (const float4*)S;
    const int dbase = ds * 64;
#pragma unroll 8
    for (int i = 0; i < 64; ++i) {
      const int d = dbase + i;
      float4 w = wp4[d * 32 + kg];    // Wpsi[d][k0..k0+4)
      float4 a = at4[d];              // At[d][0..4) — uniform-ish broadcast
      fma4(acc0, a.x, w);
      fma4(acc1, a.y, w);
      fma4(acc2, a.z, w);
      fma4(acc3, a.w, w);
    }
    float4* qp4 = (float4*)(S + 2048);
    qp4[(ds*4+0)*32 + kg] = acc0;
    qp4[(ds*4+1)*32 + kg] = acc1;
    qp4[(ds*4+2)*32 + kg] = acc2;
    qp4[(ds*4+3)*32 + kg] = acc3;
  }
  __syncthreads();

  // ---- q-reduce over 8 d-splits -> qt[k][4] ----
  {
#pragma unroll
    for (int e = tid; e < 512; e += 256) {
      const int r = e & 3;
      const int k = e >> 2;
      float s = 0.f;
#pragma unroll
      for (int ds = 0; ds < 8; ++ds) s += S[2048 + (ds*4 + r)*128 + k];
      S[6144 + k*4 + r] = s;
    }
  }
  __syncthreads();

  // ---- phase C: uS[r][dd] = sum_k qt[k][r] * WphiT[k][dd] ----
  // q via uniform LDS broadcast (no shuffles), WphiT coalesced scalar loads.
  {
    float acc[8] = {0.f,0.f,0.f,0.f,0.f,0.f,0.f,0.f};
    const float4* qt4 = (const float4*)(S + 6144);
#pragma unroll 4
    for (int k = 0; k < 128; ++k) {
      float w0 = WphiT[k*512 + tid];
      float w1 = WphiT[k*512 + tid + 256];
      float4 q = qt4[k];              // uniform address -> broadcast
      acc[0] = fmaf(q.x, w0, acc[0]);
      acc[1] = fmaf(q.y, w0, acc[1]);
      acc[2] = fmaf(q.z, w0, acc[2]);
      acc[3] = fmaf(q.w, w0, acc[3]);
      acc[4] = fmaf(q.x, w1, acc[4]);
      acc[5] = fmaf(q.y, w1, acc[5]);
      acc[6] = fmaf(q.z, w1, acc[6]);
      acc[7] = fmaf(q.w, w1, acc[7]);
    }
    // At is dead; overwrite S[0,2048) with u. (Writes race nothing: no reads
    // of this region between the reduce barrier and the barrier below.)
#pragma unroll
    for (int r = 0; r < 4; ++r) {
      S[r*512 + tid]       = acc[r];
      S[r*512 + tid + 256] = acc[4+r];
    }
  }
  __syncthreads();

  // ---- phase D: wave = one g-row; stream V, beta = u.v, softmax over a ----
  {
    const int r = wave;
    const size_t g = (size_t)(g0 + r);
    const float4* vrow = (const float4*)V + g * 2048;   // 16 x 512 floats
    const float4* ur   = (const float4*)S + r * 128;
    const float4 uf0 = ur[lane*2];
    const float4 uf1 = ur[lane*2 + 1];
    float acc[16];
#pragma unroll
    for (int ag = 0; ag < 4; ++ag) {
      float4 va[8];
#pragma unroll
      for (int j = 0; j < 4; ++j) {
        va[j*2]   = vrow[(ag*4 + j)*128 + lane*2];
        va[j*2+1] = vrow[(ag*4 + j)*128 + lane*2 + 1];
      }
#pragma unroll
      for (int j = 0; j < 4; ++j) {
        float s;
        s = uf0.x * va[j*2].x;
        s = fmaf(uf0.y, va[j*2].y, s);
        s = fmaf(uf0.z, va[j*2].z, s);
        s = fmaf(uf0.w, va[j*2].w, s);
        s = fmaf(uf1.x, va[j*2+1].x, s);
        s = fmaf(uf1.y, va[j*2+1].y, s);
        s = fmaf(uf1.z, va[j*2+1].z, s);
        s = fmaf(uf1.w, va[j*2+1].w, s);
        acc[ag*4 + j] = s;
      }
    }
#pragma unroll
    for (int a = 0; a < 16; ++a) {
      float v = acc[a];
      v += __shfl_xor(v, 32, 64);
      v += __shfl_xor(v, 16, 64);
      v += __shfl_xor(v,  8, 64);
      v += __shfl_xor(v,  4, 64);
      v += __shfl_xor(v,  2, 64);
      v += __shfl_xor(v,  1, 64);
      acc[a] = v;
    }
    float mx = acc[0];
#pragma unroll
    for (int a = 1; a < 16; ++a) mx = fmaxf(mx, acc[a]);
    float ssum = 0.f;
#pragma unroll
    for (int a = 0; a < 16; ++a) { acc[a] = __expf(acc[a] - mx); ssum += acc[a]; }
    const float inv = 1.0f / ssum;
    if (lane == 0) {
      float4* o4 = (float4*)(Out + g * 16);
      o4[0] = make_float4(acc[0]*inv,  acc[1]*inv,  acc[2]*inv,  acc[3]*inv);
      o4[1] = make_float4(acc[4]*inv,  acc[5]*inv,  acc[6]*inv,  acc[7]*inv);
      o4[2] = make_float4(acc[8]*inv,  acc[9]*inv,  acc[10]*inv, acc[11]*inv);
      o4[3] = make_float4(acc[12]*inv, acc[13]*inv, acc[14]*inv, acc[15]*inv);
    }
  }
}

extern "C" void kernel_launch(void* const* d_in, const int* in_sizes, int n_in,
                              void* d_out, int out_size, void* d_ws, size_t ws_size,
                              hipStream_t stream) {
  (void)in_sizes; (void)n_in; (void)out_size; (void)ws_size;
  const float* A    = (const float*)d_in[0];  // agent_observation (128,32,512)
  const float* V    = (const float*)d_in[1];  // visible_observations (128,32,16,512)
  const float* Wpsi = (const float*)d_in[2];  // (512,128)
  const float* Wphi = (const float*)d_in[3];  // (512,128)
  float* Out   = (float*)d_out;               // (4096,16) fp32
  float* WphiT = (float*)d_ws;                // 256KB scratch

  transpose_wphi_k<<<256, 256, 0, stream>>>(Wphi, WphiT);
  entity_attn_k<<<1024, 256, 0, stream>>>(A, V, Wpsi, WphiT, Out);
}